// Round 11
// baseline (636.806 us; speedup 1.0000x reference)
//
#include <hip/hip_runtime.h>
#include <hip/hip_bf16.h>
#include <math.h>

#define N0c 120000
#define N1c 20000
#define N2c 6000
#define N3c 1600
#define E1c 480000
#define E2c 144000
#define E3c 38400

#define HB1 120   // hist/scatter blocks for conv1 (1250 bins of dst>>4)
#define HB2 120   // hist/scatter blocks for conv2 cube sort
#define HB3 40    // hist/scatter blocks for conv3 cube sort
#define CVT2B 2000  // 125*64*64/256
#define CVT3B 4000  // 125*128*64/256
#define SS0B  469   // (120000+255)/256

typedef __attribute__((ext_vector_type(8))) short short8;
typedef __attribute__((ext_vector_type(4))) float f32x4;

__device__ __forceinline__ float eluf(float x) {
    return x > 0.0f ? x : expm1f(x);
}

__device__ __forceinline__ unsigned f2sort(float f) {
    unsigned u = __float_as_uint(f);
    return (u & 0x80000000u) ? ~u : (u | 0x80000000u);
}
__device__ __forceinline__ float sort2f(unsigned u) {
    unsigned bits = (u & 0x80000000u) ? (u & 0x7FFFFFFFu) : ~u;
    return __uint_as_float(bits);
}
__device__ __forceinline__ unsigned short f2bf(float v) {
    unsigned u = __float_as_uint(v);
    unsigned r = (u + 0x7FFFu + ((u >> 16) & 1u)) >> 16;   // RNE
    return (unsigned short)r;
}

// ---- STAGE A: all feature-independent prep, one kernel, blockIdx ranges ----
__global__ __launch_bounds__(256) void hist_all(
    const int* __restrict__ edge1, const int* __restrict__ edge2,
    const int* __restrict__ edge3,
    const float* __restrict__ pseudo2, const float* __restrict__ pseudo3,
    const float* __restrict__ W2, const float* __restrict__ W3,
    const float* __restrict__ x0, const int* __restrict__ cluster0,
    int* __restrict__ blockCnt1,
    int* __restrict__ blockCnt2, int* __restrict__ cntD2,
    int* __restrict__ blockCnt3, int* __restrict__ cntD3,
    unsigned short* __restrict__ W2t, unsigned short* __restrict__ W3t,
    unsigned* __restrict__ xm1)
{
    __shared__ int h[1250];
    int b = blockIdx.x, t = threadIdx.x;
    if (b < HB1) {
        for (int i = t; i < 1250; i += 256) h[i] = 0;
        __syncthreads();
        for (int e = b * 256 + t; e < E1c; e += HB1 * 256)
            atomicAdd(&h[edge1[E1c + e] >> 4], 1);
        __syncthreads();
        for (int i = t; i < 1250; i += 256) blockCnt1[i * HB1 + b] = h[i];
    } else if (b < HB1 + HB2 + HB3) {
        bool is2 = b < HB1 + HB2;
        int rb = is2 ? (b - HB1) : (b - HB1 - HB2);
        int nblk = is2 ? HB2 : HB3;
        int E = is2 ? E2c : E3c;
        const int* edge = is2 ? edge2 : edge3;
        const float* pseudo = is2 ? pseudo2 : pseudo3;
        int* blockCnt = is2 ? blockCnt2 : blockCnt3;
        int* dstCnt = is2 ? cntD2 : cntD3;
        int nb = is2 ? HB2 : HB3;
        if (t < 64) h[t] = 0;
        __syncthreads();
        for (int e = rb * 256 + t; e < E; e += nblk * 256) {
            int c = 0, mul = 1;
            #pragma unroll
            for (int d = 0; d < 3; d++) {
                float p = pseudo[e * 3 + d] * 4.0f;
                float l = fminf(fmaxf(floorf(p), 0.0f), 3.0f);
                c += (int)l * mul;
                mul <<= 2;
            }
            atomicAdd(&h[c], 1);
            atomicAdd(&dstCnt[edge[E + e]], 1);
        }
        __syncthreads();
        if (t < 64) blockCnt[t * nb + rb] = h[t];
    } else if (b < HB1 + HB2 + HB3 + CVT2B) {
        int idx = (b - (HB1 + HB2 + HB3)) * 256 + t;
        if (idx < 125 * 64 * 64) {
            int ic = idx & 63, kn = idx >> 6;
            int n = kn & 63, k = kn >> 6;
            W2t[idx] = f2bf(W2[((size_t)k * 64 + ic) * 64 + n]);
        }
    } else if (b < HB1 + HB2 + HB3 + CVT2B + CVT3B) {
        int idx = (b - (HB1 + HB2 + HB3 + CVT2B)) * 256 + t;
        if (idx < 125 * 128 * 64) {
            int ic = idx & 63, kn = idx >> 6;
            int n = kn & 127, k = kn >> 7;
            W3t[idx] = f2bf(W3[((size_t)k * 64 + ic) * 128 + n]);
        }
    } else {
        int idx = (b - (HB1 + HB2 + HB3 + CVT2B + CVT3B)) * 256 + t;
        if (idx < N0c)
            atomicMax(&xm1[cluster0[idx]], f2sort(x0[idx]));
    }
}

// flat exclusive scan over cnt[0..n) -> off[]; samples start[j/stride] at
// stride boundaries and start[n/stride] = total. One 256-thread block.
__device__ void flat_scan(const int* __restrict__ cnt, int* __restrict__ off,
                          int n, int stride, int* __restrict__ start,
                          int* ps) {
    int t = threadIdx.x;
    int items = (n + 255) >> 8;
    int base = t * items;
    int s = 0;
    for (int i = 0; i < items; i++) {
        int j = base + i;
        if (j < n) s += cnt[j];
    }
    ps[t] = s;
    __syncthreads();
    for (int ofs = 1; ofs < 256; ofs <<= 1) {
        int add = (t >= ofs) ? ps[t - ofs] : 0;
        __syncthreads();
        ps[t] += add;
        __syncthreads();
    }
    int run = (t == 0) ? 0 : ps[t - 1];
    for (int i = 0; i < items; i++) {
        int j = base + i;
        if (j < n) {
            off[j] = run;
            if (j % stride == 0) start[j / stride] = run;
            run += cnt[j];
        }
    }
    if (t == 255) start[n / stride] = run;
    __syncthreads();
}

// ---- STAGE B: all planning via flat scans ----
__global__ __launch_bounds__(256) void plan_all(
    const int* __restrict__ blockCnt1, int* __restrict__ start1,
    int* __restrict__ blockOff1,
    const int* __restrict__ blockCnt2, int* __restrict__ binCnt2,
    int* __restrict__ binStart2, int* __restrict__ blockOff2,
    int* __restrict__ blkPrefix2, int* __restrict__ chunkBin2,
    int* __restrict__ chunkOff2,
    const int* __restrict__ blockCnt3, int* __restrict__ binCnt3,
    int* __restrict__ binStart3, int* __restrict__ blockOff3,
    int* __restrict__ blkPrefix3, int* __restrict__ chunkBin3,
    int* __restrict__ chunkOff3)
{
    __shared__ int ps[256];
    __shared__ int ps64[64];
    int t = threadIdx.x;

    flat_scan(blockCnt1, blockOff1, 1250 * HB1, HB1, start1, ps);
    flat_scan(blockCnt2, blockOff2, 64 * HB2, HB2, binStart2, ps);
    flat_scan(blockCnt3, blockOff3, 64 * HB3, HB3, binStart3, ps);

    // conv2 finalize: binCnt, blkPrefix, chunk map (chunk = 64 edges)
    int tot2 = 0;
    if (t < 64) {
        tot2 = binStart2[t + 1] - binStart2[t];
        binCnt2[t] = tot2;
        ps64[t] = (tot2 + 63) >> 6;
    }
    __syncthreads();
    if (t == 0) {
        int p = 0;
        for (int c = 0; c < 64; c++) {
            int n = ps64[c];
            ps64[c] = p;
            p += n;
        }
        blkPrefix2[64] = p;
    }
    __syncthreads();
    if (t < 64) {
        blkPrefix2[t] = ps64[t];
        int nch = (tot2 + 63) >> 6;
        for (int j = 0; j < nch; j++) {
            chunkBin2[ps64[t] + j] = t;
            chunkOff2[ps64[t] + j] = j;
        }
    }
    __syncthreads();

    // conv3 finalize
    int tot3 = 0;
    if (t < 64) {
        tot3 = binStart3[t + 1] - binStart3[t];
        binCnt3[t] = tot3;
        ps64[t] = (tot3 + 63) >> 6;
    }
    __syncthreads();
    if (t == 0) {
        int p = 0;
        for (int c = 0; c < 64; c++) {
            int n = ps64[c];
            ps64[c] = p;
            p += n;
        }
        blkPrefix3[64] = p;
    }
    __syncthreads();
    if (t < 64) {
        blkPrefix3[t] = ps64[t];
        int nch = (tot3 + 63) >> 6;
        for (int j = 0; j < nch; j++) {
            chunkBin3[ps64[t] + j] = t;
            chunkOff3[ps64[t] + j] = j;
        }
    }
}

// ---- STAGE C: scatter EDGE RECORDS (coalesced reads, scattered writes) ----
// rec = int4 { meta, f0, f1, f2 }.
// conv1 meta: src | (dst&15)<<16 | kbase<<20.  conv2/3 meta: src | dst<<16.
__global__ __launch_bounds__(256) void scatter_all(
    const int* __restrict__ edge1, const float* __restrict__ pseudo1,
    const int* __restrict__ edge2, const float* __restrict__ pseudo2,
    const int* __restrict__ edge3, const float* __restrict__ pseudo3,
    const int* __restrict__ blockOff1, const int* __restrict__ blockOff2,
    const int* __restrict__ blockOff3,
    int4* __restrict__ rec1, int4* __restrict__ rec2, int4* __restrict__ rec3,
    unsigned* __restrict__ xm1)
{
    __shared__ int cur[1250];
    int b = blockIdx.x, t = threadIdx.x;
    if (b < HB1) {
        for (int i = t; i < 1250; i += 256) cur[i] = blockOff1[(size_t)i * HB1 + b];
        __syncthreads();
        for (int e = b * 256 + t; e < E1c; e += HB1 * 256) {
            int src = edge1[e], dst = edge1[E1c + e];
            float f[3];
            int kbase = 0, mul5 = 1;
            #pragma unroll
            for (int d = 0; d < 3; d++) {
                float pp = pseudo1[e * 3 + d] * 4.0f;
                float l = fminf(fmaxf(floorf(pp), 0.0f), 3.0f);
                f[d] = pp - l;
                kbase += (int)l * mul5;
                mul5 *= 5;
            }
            int p = atomicAdd(&cur[dst >> 4], 1);
            rec1[p] = make_int4(src | ((dst & 15) << 16) | (kbase << 20),
                                __float_as_int(f[0]), __float_as_int(f[1]),
                                __float_as_int(f[2]));
        }
    } else if (b < HB1 + HB2 + HB3) {
        bool is2 = b < HB1 + HB2;
        int rb = is2 ? (b - HB1) : (b - HB1 - HB2);
        int nblk = is2 ? HB2 : HB3;
        int E = is2 ? E2c : E3c;
        const int* edge = is2 ? edge2 : edge3;
        const float* pseudo = is2 ? pseudo2 : pseudo3;
        const int* blockOff = is2 ? blockOff2 : blockOff3;
        int4* rec = is2 ? rec2 : rec3;
        int nb = is2 ? HB2 : HB3;
        if (t < 64) cur[t] = blockOff[(size_t)t * nb + rb];
        __syncthreads();
        for (int e = rb * 256 + t; e < E; e += nblk * 256) {
            int src = edge[e], dst = edge[E + e];
            float f[3];
            int c = 0, mul = 1;
            #pragma unroll
            for (int d = 0; d < 3; d++) {
                float pp = pseudo[e * 3 + d] * 4.0f;
                float l = fminf(fmaxf(floorf(pp), 0.0f), 3.0f);
                f[d] = pp - l;
                c += (int)l * mul;
                mul <<= 2;
            }
            int p = atomicAdd(&cur[c], 1);
            rec[p] = make_int4(src | (dst << 16),
                               __float_as_int(f[0]), __float_as_int(f[1]),
                               __float_as_int(f[2]));
        }
    } else {
        int idx = (b - (HB1 + HB2 + HB3)) * 256 + t;
        if (idx < N1c) {
            float f = sort2f(xm1[idx]);
            unsigned bb = __float_as_uint(f);
            if ((bb & 0x7F800000u) == 0x7F800000u) f = 0.0f;
            ((float*)xm1)[idx] = f;
        }
    }
}

// ---- conv1 (C_in=1): per-16-node block, LDS knot accumulation + tiny GEMM,
// epilogue pools straight into xm2 (sortable-uint atomicMax). Reads records.
__global__ __launch_bounds__(256) void conv1_block(
    const int4* __restrict__ rec, const float* __restrict__ x,
    const int* __restrict__ start,
    const float* __restrict__ W, const float* __restrict__ root,
    const float* __restrict__ bias, const int* __restrict__ cl,
    unsigned* __restrict__ xmOut) {
    __shared__ float T[16][128];
    __shared__ int degL[16];
    int b = blockIdx.x;
    for (int j = threadIdx.x; j < 2048; j += 256) ((float*)T)[j] = 0.0f;
    if (threadIdx.x < 16) degL[threadIdx.x] = 0;
    __syncthreads();
    int s0 = start[b], s1 = start[b + 1];
    for (int i = s0 + threadIdx.x; i < s1; i += 256) {
        int4 r = rec[i];
        int src = r.x & 0xFFFF;
        int ln = (r.x >> 16) & 15;
        int kbase = r.x >> 20;
        float f0 = __int_as_float(r.y);
        float f1 = __int_as_float(r.z);
        float f2 = __int_as_float(r.w);
        float xv = x[src];
        #pragma unroll
        for (int s = 0; s < 8; s++) {
            int b0 = s & 1, b1 = (s >> 1) & 1, b2 = (s >> 2) & 1;
            float w0 = b0 ? f0 : 1.0f - f0;
            float w1 = b1 ? f1 : 1.0f - f1;
            float w2 = b2 ? f2 : 1.0f - f2;
            int k = kbase + b0 + 5 * b1 + 25 * b2;
            atomicAdd(&T[ln][k], xv * w0 * w1 * w2);
        }
        atomicAdd(&degL[ln], 1);
    }
    __syncthreads();
    int w = threadIdx.x >> 6, lane = threadIdx.x & 63;
    float acc[4] = {0.0f, 0.0f, 0.0f, 0.0f};
    for (int k = 0; k < 125; k++) {
        float wv = W[(k << 6) + lane];
        #pragma unroll
        for (int j = 0; j < 4; j++)
            acc[j] = fmaf(T[w + 4 * j][k], wv, acc[j]);
    }
    int v0 = b << 4;
    #pragma unroll
    for (int j = 0; j < 4; j++) {
        int ln = w + 4 * j;
        int v = v0 + ln;
        float d = fmaxf((float)degL[ln], 1.0f);
        float val = eluf(acc[j] / d + x[v] * root[lane] + bias[lane]);
        atomicMax(&xmOut[((size_t)cl[v] << 6) + lane], f2sort(val));
    }
}

// decode pooled sortable-uint buffer -> fp32 (in place) + bf16 copy
__global__ void decode_cvt(unsigned* __restrict__ buf,
                           unsigned short* __restrict__ xb, int total) {
    int idx = blockIdx.x * blockDim.x + threadIdx.x;
    if (idx >= total) return;
    float f = sort2f(buf[idx]);
    unsigned b = __float_as_uint(f);
    if ((b & 0x7F800000u) == 0x7F800000u) f = 0.0f;
    ((float*)buf)[idx] = f;
    xb[idx] = f2bf(f);
}

__global__ void segmax_decode(unsigned* __restrict__ buf, int total) {
    int idx = blockIdx.x * blockDim.x + threadIdx.x;
    if (idx >= total) return;
    float f = sort2f(buf[idx]);
    unsigned b = __float_as_uint(f);
    if ((b & 0x7F800000u) == 0x7F800000u) f = 0.0f;
    ((float*)buf)[idx] = f;
}

// Binned spline-conv via bf16 MFMA. Wave = 64 edges x 64 cols:
// 4 row-tiles x 4 N-tiles of 16x16x32. A-frags in regs reused over 8 taps;
// B batched per tap from L2; per-tap C scaled by basis; coalesced atomicAdd.
template<int COUT>
__global__ __launch_bounds__(256) void spline_mfma(
    const int4* __restrict__ recs,
    const unsigned short* __restrict__ Wt,
    const unsigned short* __restrict__ xb,
    const int* __restrict__ binStart,
    const int* __restrict__ binCnt,
    const int* __restrict__ blkPrefix,
    const int* __restrict__ chunkBin,
    const int* __restrict__ chunkOff,
    float* __restrict__ agg)
{
    __shared__ float basisS[4][8][64];
    __shared__ int srcS[4][64];
    __shared__ int dstS[4][64];

    int w = threadIdx.x >> 6, lane = threadIdx.x & 63;
    int c = blockIdx.x * 4 + w;
    if (c >= blkPrefix[64]) return;
    int bin = chunkBin[c];
    int chunk = chunkOff[c];
    int cnt = binCnt[bin];

    {
        int pos = chunk * 64 + lane;
        bool act = pos < cnt;
        int4 r = act ? recs[binStart[bin] + pos] : make_int4(0, 0, 0, 0);
        srcS[w][lane] = r.x & 0xFFFF;
        dstS[w][lane] = act ? (r.x >> 16) : -1;
        float f0 = __int_as_float(r.y);
        float f1 = __int_as_float(r.z);
        float f2 = __int_as_float(r.w);
        #pragma unroll
        for (int s = 0; s < 8; s++) {
            float w0 = (s & 1) ? f0 : 1.0f - f0;
            float w1 = (s & 2) ? f1 : 1.0f - f1;
            float w2 = (s & 4) ? f2 : 1.0f - f2;
            basisS[w][s][lane] = act ? (w0 * w1 * w2) : 0.0f;
        }
    }
    __builtin_amdgcn_wave_barrier();
    __threadfence_block();

    int lo0 = bin & 3, lo1 = (bin >> 2) & 3, lo2 = bin >> 4;
    int kbase = lo0 + 5 * lo1 + 25 * lo2;
    int colOff = (COUT == 128) ? (blockIdx.y << 6) : 0;
    int q = lane >> 4;        // quad
    int mcol = lane & 15;

    short8 afr[4][2];
    #pragma unroll
    for (int rt = 0; rt < 4; rt++) {
        int src = srcS[w][rt * 16 + mcol];
        const unsigned short* xr = xb + ((size_t)src << 6) + q * 8;
        afr[rt][0] = *(const short8*)(xr);
        afr[rt][1] = *(const short8*)(xr + 32);
    }

    f32x4 acc[4][4];
    #pragma unroll
    for (int rt = 0; rt < 4; rt++)
        #pragma unroll
        for (int nt = 0; nt < 4; nt++)
            acc[rt][nt] = (f32x4){0.0f, 0.0f, 0.0f, 0.0f};
    const f32x4 zero4 = {0.0f, 0.0f, 0.0f, 0.0f};

    #pragma unroll 1
    for (int s = 0; s < 8; s++) {
        int k = kbase + (s & 1) + 5 * ((s >> 1) & 1) + 25 * (s >> 2);
        const unsigned short* Wk = Wt + ((size_t)k * COUT + colOff) * 64;
        short8 bfr[4][2];
        #pragma unroll
        for (int nt = 0; nt < 4; nt++) {
            const unsigned short* Wn = Wk + (size_t)(nt * 16 + mcol) * 64 + q * 8;
            bfr[nt][0] = *(const short8*)(Wn);
            bfr[nt][1] = *(const short8*)(Wn + 32);
        }
        #pragma unroll
        for (int rt = 0; rt < 4; rt++) {
            f32x4 ct[4];
            #pragma unroll
            for (int nt = 0; nt < 4; nt++) {
                ct[nt] = __builtin_amdgcn_mfma_f32_16x16x32_bf16(afr[rt][0], bfr[nt][0], zero4, 0, 0, 0);
                ct[nt] = __builtin_amdgcn_mfma_f32_16x16x32_bf16(afr[rt][1], bfr[nt][1], ct[nt], 0, 0, 0);
            }
            #pragma unroll
            for (int r = 0; r < 4; r++) {
                float bs = basisS[w][s][rt * 16 + q * 4 + r];
                #pragma unroll
                for (int nt = 0; nt < 4; nt++)
                    acc[rt][nt][r] = fmaf(bs, ct[nt][r], acc[rt][nt][r]);
            }
        }
    }

    // Epilogue: row-coalesced atomicAdd from C layout (row = q*4+r).
    #pragma unroll
    for (int rt = 0; rt < 4; rt++) {
        #pragma unroll
        for (int r = 0; r < 4; r++) {
            int d = dstS[w][rt * 16 + q * 4 + r];
            if (d >= 0) {
                float* ap = agg + (size_t)d * COUT + colOff + mcol;
                #pragma unroll
                for (int nt = 0; nt < 4; nt++)
                    atomicAdd(ap + nt * 16, acc[rt][nt][r]);
            }
        }
    }
}

// node update (mean + root matmul + bias + elu) + pool scatter, COUT=64.
__global__ __launch_bounds__(256) void node_update64(
    const float* __restrict__ agg, const int* __restrict__ deg,
    const float* __restrict__ xm, const float* __restrict__ root,
    const float* __restrict__ bias, const int* __restrict__ cl,
    unsigned* __restrict__ xmOut, int nNodes) {
    __shared__ float xsh[4][64];
    int w = threadIdx.x >> 6, lane = threadIdx.x & 63;
    int v = blockIdx.x * 4 + w;
    if (v >= nNodes) return;
    xsh[w][lane] = xm[((size_t)v << 6) + lane];
    float a = agg[((size_t)v << 6) + lane] / fmaxf((float)deg[v], 1.0f);
    float r = 0.0f;
    #pragma unroll 8
    for (int i = 0; i < 64; i++)
        r = fmaf(xsh[w][i], root[(i << 6) + lane], r);
    float val = eluf(a + r + bias[lane]);
    atomicMax(&xmOut[((size_t)cl[v] << 6) + lane], f2sort(val));
}

// node update + pool scatter, COUT=128 (2 channels/lane).
__global__ __launch_bounds__(256) void node_update128(
    const float* __restrict__ agg, const int* __restrict__ deg,
    const float* __restrict__ xm, const float* __restrict__ root,
    const float* __restrict__ bias, const int* __restrict__ cl,
    unsigned* __restrict__ xmOut, int nNodes) {
    __shared__ float xsh[4][64];
    int w = threadIdx.x >> 6, lane = threadIdx.x & 63;
    int v = blockIdx.x * 4 + w;
    if (v >= nNodes) return;
    xsh[w][lane] = xm[((size_t)v << 6) + lane];
    float dinv = 1.0f / fmaxf((float)deg[v], 1.0f);
    float a0 = agg[((size_t)v << 7) + lane] * dinv;
    float a1 = agg[((size_t)v << 7) + 64 + lane] * dinv;
    float r0 = 0.0f, r1 = 0.0f;
    #pragma unroll 8
    for (int i = 0; i < 64; i++) {
        float xi = xsh[w][i];
        r0 = fmaf(xi, root[(i << 7) + lane], r0);
        r1 = fmaf(xi, root[(i << 7) + 64 + lane], r1);
    }
    unsigned* orow = xmOut + ((size_t)cl[v] << 7);
    atomicMax(&orow[lane], f2sort(eluf(a0 + r0 + bias[lane])));
    atomicMax(&orow[64 + lane], f2sort(eluf(a1 + r1 + bias[lane + 64])));
}

// fc1 k-split: grid (64 rows, 8 k-slices). Partial dot over 128 inputs,
// atomicAdd into h (zero-initialized).
__global__ __launch_bounds__(256) void fc1_split(
    const float* __restrict__ xin, const float* __restrict__ w1,
    float* __restrict__ h) {
    __shared__ float xsh[128];
    int row = blockIdx.x, ks = blockIdx.y;
    int o = threadIdx.x;
    if (o < 128) xsh[o] = xin[row * 1024 + ks * 128 + o];
    __syncthreads();
    float acc = 0.0f;
    const float* wp = w1 + (size_t)ks * 128 * 256 + o;
    #pragma unroll 8
    for (int i = 0; i < 128; i++)
        acc = fmaf(xsh[i], wp[i * 256], acc);
    atomicAdd(&h[row * 256 + o], acc);
}

// fc2 + log_softmax: elu(h+b1) @ w2 + b2. One block (64 thr) per row.
__global__ __launch_bounds__(64) void fc2_k(
    const float* __restrict__ h, const float* __restrict__ b1,
    const float* __restrict__ w2, const float* __restrict__ b2,
    float* __restrict__ out) {
    __shared__ float hs[256];
    __shared__ float lg[10];
    int row = blockIdx.x;
    int t = threadIdx.x;
    for (int i = t; i < 256; i += 64) hs[i] = eluf(h[row * 256 + i] + b1[i]);
    __syncthreads();
    if (t < 10) {
        float a = b2[t];
        for (int i = 0; i < 256; i++) a = fmaf(hs[i], w2[i * 10 + t], a);
        lg[t] = a;
    }
    __syncthreads();
    if (t < 10) {
        float m = -1e30f;
        #pragma unroll
        for (int j = 0; j < 10; j++) m = fmaxf(m, lg[j]);
        float sum = 0.0f;
        #pragma unroll
        for (int j = 0; j < 10; j++) sum += expf(lg[j] - m);
        out[row * 10 + t] = lg[t] - m - logf(sum);
    }
}

extern "C" void kernel_launch(void* const* d_in, const int* in_sizes, int n_in,
                              void* d_out, int out_size, void* d_ws, size_t ws_size,
                              hipStream_t stream) {
    const float* x0      = (const float*)d_in[0];
    const int*   cluster0= (const int*)d_in[1];
    const int*   edge1   = (const int*)d_in[2];
    const float* pseudo1 = (const float*)d_in[3];
    const float* W1      = (const float*)d_in[4];
    const float* root1   = (const float*)d_in[5];
    const float* b1      = (const float*)d_in[6];
    const int*   cluster1= (const int*)d_in[7];
    const int*   edge2   = (const int*)d_in[8];
    const float* pseudo2 = (const float*)d_in[9];
    const float* W2      = (const float*)d_in[10];
    const float* root2   = (const float*)d_in[11];
    const float* b2      = (const float*)d_in[12];
    const int*   cluster2= (const int*)d_in[13];
    const int*   edge3   = (const int*)d_in[14];
    const float* pseudo3 = (const float*)d_in[15];
    const float* W3      = (const float*)d_in[16];
    const float* root3   = (const float*)d_in[17];
    const float* b3      = (const float*)d_in[18];
    const int*   cluster3= (const int*)d_in[19];
    const float* fc1_w   = (const float*)d_in[20];
    const float* fc1_b   = (const float*)d_in[21];
    const float* fc2_w   = (const float*)d_in[22];
    const float* fc2_b   = (const float*)d_in[23];
    float* out = (float*)d_out;

    float* ws = (float*)d_ws;
    size_t off = 0;
    // ---- zeroed region ----
    float* xm1  = ws + off; off += 20480;
    float* xm2  = ws + off; off += (size_t)N2c * 64;
    float* xm3  = ws + off; off += (size_t)N3c * 64;
    float* xm4  = ws + off; off += 512 * 128;
    float* agg2 = ws + off; off += (size_t)N2c * 64;
    float* agg3 = ws + off; off += (size_t)N3c * 128;
    float* h1   = ws + off; off += 64 * 256;
    int* cntD2   = (int*)(ws + off); off += 6016;
    int* cntD3   = (int*)(ws + off); off += 1664;
    size_t zeroFloats = off;
    // ---- non-zeroed region (fully written before read every launch) ----
    int4* rec1 = (int4*)(ws + off); off += (size_t)E1c * 4;
    int4* rec2 = (int4*)(ws + off); off += (size_t)E2c * 4;
    int4* rec3 = (int4*)(ws + off); off += (size_t)E3c * 4;
    unsigned short* W2t = (unsigned short*)(ws + off); off += 256000;
    unsigned short* W3t = (unsigned short*)(ws + off); off += 512000;
    unsigned short* xb2 = (unsigned short*)(ws + off); off += 192000;
    unsigned short* xb3 = (unsigned short*)(ws + off); off += 51200;
    int* start1    = (int*)(ws + off); off += 1280;
    int* blockCnt1 = (int*)(ws + off); off += HB1 * 1250;
    int* blockOff1 = (int*)(ws + off); off += HB1 * 1250;
    int* blockCnt2 = (int*)(ws + off); off += HB2 * 64;
    int* blockOff2 = (int*)(ws + off); off += HB2 * 64;
    int* blockCnt3 = (int*)(ws + off); off += HB3 * 64;
    int* blockOff3 = (int*)(ws + off); off += HB3 * 64;
    int* binCnt2   = (int*)(ws + off); off += 64;
    int* binStart2 = (int*)(ws + off); off += 80;
    int* blkPrefix2= (int*)(ws + off); off += 80;
    int* chunkBin2 = (int*)(ws + off); off += 2560;
    int* chunkOff2 = (int*)(ws + off); off += 2560;
    int* binCnt3   = (int*)(ws + off); off += 64;
    int* binStart3 = (int*)(ws + off); off += 80;
    int* blkPrefix3= (int*)(ws + off); off += 80;
    int* chunkBin3 = (int*)(ws + off); off += 768;
    int* chunkOff3 = (int*)(ws + off); off += 768;

    hipMemsetAsync(d_ws, 0, zeroFloats * sizeof(float), stream);

    // A: hists + dst-degrees + weight conversion + pool0 scatter
    hist_all<<<HB1 + HB2 + HB3 + CVT2B + CVT3B + SS0B, 256, 0, stream>>>(
        edge1, edge2, edge3, pseudo2, pseudo3, W2, W3, x0, cluster0,
        blockCnt1, blockCnt2, cntD2, blockCnt3, cntD3,
        W2t, W3t, (unsigned*)xm1);

    // B: flat scans / offsets / chunk maps
    plan_all<<<1, 256, 0, stream>>>(
        blockCnt1, start1, blockOff1,
        blockCnt2, binCnt2, binStart2, blockOff2, blkPrefix2, chunkBin2, chunkOff2,
        blockCnt3, binCnt3, binStart3, blockOff3, blkPrefix3, chunkBin3, chunkOff3);

    // C: scatter edge records + pool0 decode
    scatter_all<<<HB1 + HB2 + HB3 + (N1c + 255) / 256, 256, 0, stream>>>(
        edge1, pseudo1, edge2, pseudo2, edge3, pseudo3,
        blockOff1, blockOff2, blockOff3, rec1, rec2, rec3, (unsigned*)xm1);

    // conv1 (1->64) + pool into xm2
    conv1_block<<<1250, 256, 0, stream>>>(rec1, xm1, start1, W1, root1, b1,
                                          cluster1, (unsigned*)xm2);
    decode_cvt<<<(N2c * 64) / 256, 256, 0, stream>>>((unsigned*)xm2, xb2, N2c * 64);

    // conv2 (64->64): MFMA -> agg2 (atomic), node update + pool into xm3
    spline_mfma<64><<<dim3((E2c / 64 + 64 + 3) / 4, 1), 256, 0, stream>>>(
        rec2, W2t, xb2, binStart2, binCnt2, blkPrefix2, chunkBin2, chunkOff2, agg2);
    node_update64<<<(N2c + 3) / 4, 256, 0, stream>>>(agg2, cntD2, xm2, root2, b2,
                                                     cluster2, (unsigned*)xm3, N2c);
    decode_cvt<<<(N3c * 64) / 256, 256, 0, stream>>>((unsigned*)xm3, xb3, N3c * 64);

    // conv3 (64->128): MFMA -> agg3 (atomic), node update + pool into xm4
    spline_mfma<128><<<dim3((E3c / 64 + 64 + 3) / 4, 2), 256, 0, stream>>>(
        rec3, W3t, xb3, binStart3, binCnt3, blkPrefix3, chunkBin3, chunkOff3, agg3);
    node_update128<<<(N3c + 3) / 4, 256, 0, stream>>>(agg3, cntD3, xm3, root3, b3,
                                                      cluster3, (unsigned*)xm4, N3c);
    segmax_decode<<<(512 * 128) / 256, 256, 0, stream>>>((unsigned*)xm4, 512 * 128);

    // FC head: k-split fc1 + fused fc2/log_softmax
    fc1_split<<<dim3(64, 8), 256, 0, stream>>>(xm4, fc1_w, h1);
    fc2_k<<<64, 64, 0, stream>>>(h1, fc1_b, fc2_w, fc2_b, out);
}

// Round 12
// 347.446 us; speedup vs baseline: 1.8328x; 1.8328x over previous
//
#include <hip/hip_runtime.h>
#include <hip/hip_bf16.h>
#include <math.h>

#define N0c 120000
#define N1c 20000
#define N2c 6000
#define N3c 1600
#define E1c 480000
#define E2c 144000
#define E3c 38400

#define HB1 32    // hist/scatter blocks for conv1 (1250 bins of dst>>4)
#define HB2 120   // hist/scatter blocks for conv2 cube sort
#define HB3 40    // hist/scatter blocks for conv3 cube sort
#define CVT2B 2000  // 125*64*64/256
#define CVT3B 4000  // 125*128*64/256
#define SS0B  469   // (120000+255)/256

typedef __attribute__((ext_vector_type(8))) short short8;
typedef __attribute__((ext_vector_type(4))) float f32x4;

__device__ __forceinline__ float eluf(float x) {
    return x > 0.0f ? x : expm1f(x);
}

__device__ __forceinline__ unsigned f2sort(float f) {
    unsigned u = __float_as_uint(f);
    return (u & 0x80000000u) ? ~u : (u | 0x80000000u);
}
__device__ __forceinline__ float sort2f(unsigned u) {
    unsigned bits = (u & 0x80000000u) ? (u & 0x7FFFFFFFu) : ~u;
    return __uint_as_float(bits);
}
__device__ __forceinline__ unsigned short f2bf(float v) {
    unsigned u = __float_as_uint(v);
    unsigned r = (u + 0x7FFFu + ((u >> 16) & 1u)) >> 16;   // RNE
    return (unsigned short)r;
}

// ---- STAGE A: all feature-independent prep, one kernel, blockIdx ranges ----
__global__ __launch_bounds__(256) void hist_all(
    const int* __restrict__ edge1, const int* __restrict__ edge2,
    const int* __restrict__ edge3,
    const float* __restrict__ pseudo2, const float* __restrict__ pseudo3,
    const float* __restrict__ W2, const float* __restrict__ W3,
    const float* __restrict__ x0, const int* __restrict__ cluster0,
    int* __restrict__ blockCnt1,
    int* __restrict__ blockCnt2, int* __restrict__ cntD2,
    int* __restrict__ blockCnt3, int* __restrict__ cntD3,
    unsigned short* __restrict__ W2t, unsigned short* __restrict__ W3t,
    unsigned* __restrict__ xm1)
{
    __shared__ int h[1250];
    int b = blockIdx.x, t = threadIdx.x;
    if (b < HB1) {
        for (int i = t; i < 1250; i += 256) h[i] = 0;
        __syncthreads();
        for (int e = b * 256 + t; e < E1c; e += HB1 * 256)
            atomicAdd(&h[edge1[E1c + e] >> 4], 1);
        __syncthreads();
        for (int i = t; i < 1250; i += 256) blockCnt1[i * HB1 + b] = h[i];
    } else if (b < HB1 + HB2 + HB3) {
        bool is2 = b < HB1 + HB2;
        int rb = is2 ? (b - HB1) : (b - HB1 - HB2);
        int nblk = is2 ? HB2 : HB3;
        int E = is2 ? E2c : E3c;
        const int* edge = is2 ? edge2 : edge3;
        const float* pseudo = is2 ? pseudo2 : pseudo3;
        int* blockCnt = is2 ? blockCnt2 : blockCnt3;
        int* dstCnt = is2 ? cntD2 : cntD3;
        int nb = is2 ? HB2 : HB3;
        if (t < 64) h[t] = 0;
        __syncthreads();
        for (int e = rb * 256 + t; e < E; e += nblk * 256) {
            int c = 0, mul = 1;
            #pragma unroll
            for (int d = 0; d < 3; d++) {
                float p = pseudo[e * 3 + d] * 4.0f;
                float l = fminf(fmaxf(floorf(p), 0.0f), 3.0f);
                c += (int)l * mul;
                mul <<= 2;
            }
            atomicAdd(&h[c], 1);
            atomicAdd(&dstCnt[edge[E + e]], 1);
        }
        __syncthreads();
        if (t < 64) blockCnt[t * nb + rb] = h[t];
    } else if (b < HB1 + HB2 + HB3 + CVT2B) {
        int idx = (b - (HB1 + HB2 + HB3)) * 256 + t;
        if (idx < 125 * 64 * 64) {
            int ic = idx & 63, kn = idx >> 6;
            int n = kn & 63, k = kn >> 6;
            W2t[idx] = f2bf(W2[((size_t)k * 64 + ic) * 64 + n]);
        }
    } else if (b < HB1 + HB2 + HB3 + CVT2B + CVT3B) {
        int idx = (b - (HB1 + HB2 + HB3 + CVT2B)) * 256 + t;
        if (idx < 125 * 128 * 64) {
            int ic = idx & 63, kn = idx >> 6;
            int n = kn & 127, k = kn >> 7;
            W3t[idx] = f2bf(W3[((size_t)k * 64 + ic) * 128 + n]);
        }
    } else {
        int idx = (b - (HB1 + HB2 + HB3 + CVT2B + CVT3B)) * 256 + t;
        if (idx < N0c)
            atomicMax(&xm1[cluster0[idx]], f2sort(x0[idx]));
    }
}

// ---- STAGE B1: per-bin totals (contiguous int4 row sums) + scans + chunk maps
__global__ __launch_bounds__(256) void plan_tot(
    const int* __restrict__ blockCnt1, int* __restrict__ start1,
    const int* __restrict__ blockCnt2, int* __restrict__ binCnt2,
    int* __restrict__ binStart2, int* __restrict__ blkPrefix2,
    int* __restrict__ chunkBin2, int* __restrict__ chunkOff2,
    const int* __restrict__ blockCnt3, int* __restrict__ binCnt3,
    int* __restrict__ binStart3, int* __restrict__ blkPrefix3,
    int* __restrict__ chunkBin3, int* __restrict__ chunkOff3)
{
    __shared__ int ps[256];
    __shared__ int ps64[64];
    int t = threadIdx.x;

    // conv1: thread t owns bins [5t, 5t+5); each row is HB1 contiguous ints
    int loc[5];
    int s = 0;
    #pragma unroll
    for (int i = 0; i < 5; i++) {
        int bin = t * 5 + i;
        int v = 0;
        if (bin < 1250) {
            const int4* row = (const int4*)(blockCnt1 + (size_t)bin * HB1);
            #pragma unroll
            for (int j = 0; j < HB1 / 4; j++) {
                int4 q = row[j];
                v += q.x + q.y + q.z + q.w;
            }
        }
        loc[i] = v;
        s += v;
    }
    ps[t] = s;
    __syncthreads();
    for (int ofs = 1; ofs < 256; ofs <<= 1) {
        int add = (t >= ofs) ? ps[t - ofs] : 0;
        __syncthreads();
        ps[t] += add;
        __syncthreads();
    }
    int run = (t == 0) ? 0 : ps[t - 1];
    #pragma unroll
    for (int i = 0; i < 5; i++) {
        int bin = t * 5 + i;
        if (bin < 1250) {
            start1[bin] = run;
            run += loc[i];
        }
    }
    if (t == 255) start1[1250] = run;
    __syncthreads();

    // conv2: totals, starts, chunk map (chunk = 64 edges)
    if (t < 64) {
        int v = 0;
        const int4* row = (const int4*)(blockCnt2 + (size_t)t * HB2);
        for (int j = 0; j < HB2 / 4; j++) {
            int4 q = row[j];
            v += q.x + q.y + q.z + q.w;
        }
        binCnt2[t] = v;
        ps64[t] = v;
    }
    __syncthreads();
    if (t == 0) {
        int s2 = 0, p = 0;
        for (int c = 0; c < 64; c++) {
            int v = ps64[c];
            binStart2[c] = s2;
            blkPrefix2[c] = p;
            s2 += v;
            p += (v + 63) >> 6;
        }
        binStart2[64] = s2;
        blkPrefix2[64] = p;
    }
    __syncthreads();
    if (t < 64) {
        int nch = (binCnt2[t] + 63) >> 6;
        int base = blkPrefix2[t];
        for (int j = 0; j < nch; j++) {
            chunkBin2[base + j] = t;
            chunkOff2[base + j] = j;
        }
    }
    __syncthreads();

    // conv3
    if (t < 64) {
        int v = 0;
        const int4* row = (const int4*)(blockCnt3 + (size_t)t * HB3);
        for (int j = 0; j < HB3 / 4; j++) {
            int4 q = row[j];
            v += q.x + q.y + q.z + q.w;
        }
        binCnt3[t] = v;
        ps64[t] = v;
    }
    __syncthreads();
    if (t == 0) {
        int s3 = 0, p = 0;
        for (int c = 0; c < 64; c++) {
            int v = ps64[c];
            binStart3[c] = s3;
            blkPrefix3[c] = p;
            s3 += v;
            p += (v + 63) >> 6;
        }
        binStart3[64] = s3;
        blkPrefix3[64] = p;
    }
    __syncthreads();
    if (t < 64) {
        int nch = (binCnt3[t] + 63) >> 6;
        int base = blkPrefix3[t];
        for (int j = 0; j < nch; j++) {
            chunkBin3[base + j] = t;
            chunkOff3[base + j] = j;
        }
    }
}

// ---- STAGE B2: per-(bin,block) offsets; one thread per bin-row ----
__global__ __launch_bounds__(256) void off_all(
    const int* __restrict__ blockCnt1, const int* __restrict__ start1,
    int* __restrict__ blockOff1,
    const int* __restrict__ blockCnt2, const int* __restrict__ binStart2,
    int* __restrict__ blockOff2,
    const int* __restrict__ blockCnt3, const int* __restrict__ binStart3,
    int* __restrict__ blockOff3)
{
    int r = blockIdx.x * 256 + threadIdx.x;
    if (r < 1250) {
        int run = start1[r];
        const int* c = blockCnt1 + (size_t)r * HB1;
        int* o = blockOff1 + (size_t)r * HB1;
        #pragma unroll 4
        for (int b = 0; b < HB1; b++) { o[b] = run; run += c[b]; }
    } else if (r < 1250 + 64) {
        int bin = r - 1250;
        int run = binStart2[bin];
        const int* c = blockCnt2 + (size_t)bin * HB2;
        int* o = blockOff2 + (size_t)bin * HB2;
        #pragma unroll 4
        for (int b = 0; b < HB2; b++) { o[b] = run; run += c[b]; }
    } else if (r < 1250 + 128) {
        int bin = r - 1314;
        int run = binStart3[bin];
        const int* c = blockCnt3 + (size_t)bin * HB3;
        int* o = blockOff3 + (size_t)bin * HB3;
        #pragma unroll 4
        for (int b = 0; b < HB3; b++) { o[b] = run; run += c[b]; }
    }
}

// ---- STAGE C: scatter EDGE RECORDS (coalesced reads, scattered writes) ----
// rec = int4 { meta, f0, f1, f2 }.
// conv1 meta: src | (dst&15)<<16 | kbase<<20.  conv2/3 meta: src | dst<<16.
__global__ __launch_bounds__(256) void scatter_all(
    const int* __restrict__ edge1, const float* __restrict__ pseudo1,
    const int* __restrict__ edge2, const float* __restrict__ pseudo2,
    const int* __restrict__ edge3, const float* __restrict__ pseudo3,
    const int* __restrict__ blockOff1, const int* __restrict__ blockOff2,
    const int* __restrict__ blockOff3,
    int4* __restrict__ rec1, int4* __restrict__ rec2, int4* __restrict__ rec3,
    unsigned* __restrict__ xm1)
{
    __shared__ int cur[1250];
    int b = blockIdx.x, t = threadIdx.x;
    if (b < HB1) {
        for (int i = t; i < 1250; i += 256) cur[i] = blockOff1[(size_t)i * HB1 + b];
        __syncthreads();
        for (int e = b * 256 + t; e < E1c; e += HB1 * 256) {
            int src = edge1[e], dst = edge1[E1c + e];
            float f[3];
            int kbase = 0, mul5 = 1;
            #pragma unroll
            for (int d = 0; d < 3; d++) {
                float pp = pseudo1[e * 3 + d] * 4.0f;
                float l = fminf(fmaxf(floorf(pp), 0.0f), 3.0f);
                f[d] = pp - l;
                kbase += (int)l * mul5;
                mul5 *= 5;
            }
            int p = atomicAdd(&cur[dst >> 4], 1);
            rec1[p] = make_int4(src | ((dst & 15) << 16) | (kbase << 20),
                                __float_as_int(f[0]), __float_as_int(f[1]),
                                __float_as_int(f[2]));
        }
    } else if (b < HB1 + HB2 + HB3) {
        bool is2 = b < HB1 + HB2;
        int rb = is2 ? (b - HB1) : (b - HB1 - HB2);
        int nblk = is2 ? HB2 : HB3;
        int E = is2 ? E2c : E3c;
        const int* edge = is2 ? edge2 : edge3;
        const float* pseudo = is2 ? pseudo2 : pseudo3;
        const int* blockOff = is2 ? blockOff2 : blockOff3;
        int4* rec = is2 ? rec2 : rec3;
        int nb = is2 ? HB2 : HB3;
        if (t < 64) cur[t] = blockOff[(size_t)t * nb + rb];
        __syncthreads();
        for (int e = rb * 256 + t; e < E; e += nblk * 256) {
            int src = edge[e], dst = edge[E + e];
            float f[3];
            int c = 0, mul = 1;
            #pragma unroll
            for (int d = 0; d < 3; d++) {
                float pp = pseudo[e * 3 + d] * 4.0f;
                float l = fminf(fmaxf(floorf(pp), 0.0f), 3.0f);
                f[d] = pp - l;
                c += (int)l * mul;
                mul <<= 2;
            }
            int p = atomicAdd(&cur[c], 1);
            rec[p] = make_int4(src | (dst << 16),
                               __float_as_int(f[0]), __float_as_int(f[1]),
                               __float_as_int(f[2]));
        }
    } else {
        int idx = (b - (HB1 + HB2 + HB3)) * 256 + t;
        if (idx < N1c) {
            float f = sort2f(xm1[idx]);
            unsigned bb = __float_as_uint(f);
            if ((bb & 0x7F800000u) == 0x7F800000u) f = 0.0f;
            ((float*)xm1)[idx] = f;
        }
    }
}

// ---- conv1 (C_in=1): per-16-node block, LDS knot accumulation + tiny GEMM,
// epilogue pools straight into xm2 (sortable-uint atomicMax). Reads records.
__global__ __launch_bounds__(256) void conv1_block(
    const int4* __restrict__ rec, const float* __restrict__ x,
    const int* __restrict__ start,
    const float* __restrict__ W, const float* __restrict__ root,
    const float* __restrict__ bias, const int* __restrict__ cl,
    unsigned* __restrict__ xmOut) {
    __shared__ float T[16][128];
    __shared__ int degL[16];
    int b = blockIdx.x;
    for (int j = threadIdx.x; j < 2048; j += 256) ((float*)T)[j] = 0.0f;
    if (threadIdx.x < 16) degL[threadIdx.x] = 0;
    __syncthreads();
    int s0 = start[b], s1 = start[b + 1];
    for (int i = s0 + threadIdx.x; i < s1; i += 256) {
        int4 r = rec[i];
        int src = r.x & 0xFFFF;
        int ln = (r.x >> 16) & 15;
        int kbase = r.x >> 20;
        float f0 = __int_as_float(r.y);
        float f1 = __int_as_float(r.z);
        float f2 = __int_as_float(r.w);
        float xv = x[src];
        #pragma unroll
        for (int s = 0; s < 8; s++) {
            int b0 = s & 1, b1 = (s >> 1) & 1, b2 = (s >> 2) & 1;
            float w0 = b0 ? f0 : 1.0f - f0;
            float w1 = b1 ? f1 : 1.0f - f1;
            float w2 = b2 ? f2 : 1.0f - f2;
            int k = kbase + b0 + 5 * b1 + 25 * b2;
            atomicAdd(&T[ln][k], xv * w0 * w1 * w2);
        }
        atomicAdd(&degL[ln], 1);
    }
    __syncthreads();
    int w = threadIdx.x >> 6, lane = threadIdx.x & 63;
    float acc[4] = {0.0f, 0.0f, 0.0f, 0.0f};
    for (int k = 0; k < 125; k++) {
        float wv = W[(k << 6) + lane];
        #pragma unroll
        for (int j = 0; j < 4; j++)
            acc[j] = fmaf(T[w + 4 * j][k], wv, acc[j]);
    }
    int v0 = b << 4;
    #pragma unroll
    for (int j = 0; j < 4; j++) {
        int ln = w + 4 * j;
        int v = v0 + ln;
        float d = fmaxf((float)degL[ln], 1.0f);
        float val = eluf(acc[j] / d + x[v] * root[lane] + bias[lane]);
        atomicMax(&xmOut[((size_t)cl[v] << 6) + lane], f2sort(val));
    }
}

// decode pooled sortable-uint buffer -> fp32 (in place) + bf16 copy
__global__ void decode_cvt(unsigned* __restrict__ buf,
                           unsigned short* __restrict__ xb, int total) {
    int idx = blockIdx.x * blockDim.x + threadIdx.x;
    if (idx >= total) return;
    float f = sort2f(buf[idx]);
    unsigned b = __float_as_uint(f);
    if ((b & 0x7F800000u) == 0x7F800000u) f = 0.0f;
    ((float*)buf)[idx] = f;
    xb[idx] = f2bf(f);
}

__global__ void segmax_decode(unsigned* __restrict__ buf, int total) {
    int idx = blockIdx.x * blockDim.x + threadIdx.x;
    if (idx >= total) return;
    float f = sort2f(buf[idx]);
    unsigned b = __float_as_uint(f);
    if ((b & 0x7F800000u) == 0x7F800000u) f = 0.0f;
    ((float*)buf)[idx] = f;
}

// Binned spline-conv via bf16 MFMA. Wave = 64 edges x 64 cols:
// 4 row-tiles x 4 N-tiles of 16x16x32. A-frags in regs reused over 8 taps;
// B batched per tap from L2; per-tap C scaled by basis; coalesced atomicAdd.
template<int COUT>
__global__ __launch_bounds__(256) void spline_mfma(
    const int4* __restrict__ recs,
    const unsigned short* __restrict__ Wt,
    const unsigned short* __restrict__ xb,
    const int* __restrict__ binStart,
    const int* __restrict__ binCnt,
    const int* __restrict__ blkPrefix,
    const int* __restrict__ chunkBin,
    const int* __restrict__ chunkOff,
    float* __restrict__ agg)
{
    __shared__ float basisS[4][8][64];
    __shared__ int srcS[4][64];
    __shared__ int dstS[4][64];

    int w = threadIdx.x >> 6, lane = threadIdx.x & 63;
    int c = blockIdx.x * 4 + w;
    if (c >= blkPrefix[64]) return;
    int bin = chunkBin[c];
    int chunk = chunkOff[c];
    int cnt = binCnt[bin];

    {
        int pos = chunk * 64 + lane;
        bool act = pos < cnt;
        int4 r = act ? recs[binStart[bin] + pos] : make_int4(0, 0, 0, 0);
        srcS[w][lane] = r.x & 0xFFFF;
        dstS[w][lane] = act ? (r.x >> 16) : -1;
        float f0 = __int_as_float(r.y);
        float f1 = __int_as_float(r.z);
        float f2 = __int_as_float(r.w);
        #pragma unroll
        for (int s = 0; s < 8; s++) {
            float w0 = (s & 1) ? f0 : 1.0f - f0;
            float w1 = (s & 2) ? f1 : 1.0f - f1;
            float w2 = (s & 4) ? f2 : 1.0f - f2;
            basisS[w][s][lane] = act ? (w0 * w1 * w2) : 0.0f;
        }
    }
    __builtin_amdgcn_wave_barrier();
    __threadfence_block();

    int lo0 = bin & 3, lo1 = (bin >> 2) & 3, lo2 = bin >> 4;
    int kbase = lo0 + 5 * lo1 + 25 * lo2;
    int colOff = (COUT == 128) ? (blockIdx.y << 6) : 0;
    int q = lane >> 4;        // quad
    int mcol = lane & 15;

    short8 afr[4][2];
    #pragma unroll
    for (int rt = 0; rt < 4; rt++) {
        int src = srcS[w][rt * 16 + mcol];
        const unsigned short* xr = xb + ((size_t)src << 6) + q * 8;
        afr[rt][0] = *(const short8*)(xr);
        afr[rt][1] = *(const short8*)(xr + 32);
    }

    f32x4 acc[4][4];
    #pragma unroll
    for (int rt = 0; rt < 4; rt++)
        #pragma unroll
        for (int nt = 0; nt < 4; nt++)
            acc[rt][nt] = (f32x4){0.0f, 0.0f, 0.0f, 0.0f};
    const f32x4 zero4 = {0.0f, 0.0f, 0.0f, 0.0f};

    #pragma unroll 1
    for (int s = 0; s < 8; s++) {
        int k = kbase + (s & 1) + 5 * ((s >> 1) & 1) + 25 * (s >> 2);
        const unsigned short* Wk = Wt + ((size_t)k * COUT + colOff) * 64;
        short8 bfr[4][2];
        #pragma unroll
        for (int nt = 0; nt < 4; nt++) {
            const unsigned short* Wn = Wk + (size_t)(nt * 16 + mcol) * 64 + q * 8;
            bfr[nt][0] = *(const short8*)(Wn);
            bfr[nt][1] = *(const short8*)(Wn + 32);
        }
        #pragma unroll
        for (int rt = 0; rt < 4; rt++) {
            f32x4 ct[4];
            #pragma unroll
            for (int nt = 0; nt < 4; nt++) {
                ct[nt] = __builtin_amdgcn_mfma_f32_16x16x32_bf16(afr[rt][0], bfr[nt][0], zero4, 0, 0, 0);
                ct[nt] = __builtin_amdgcn_mfma_f32_16x16x32_bf16(afr[rt][1], bfr[nt][1], ct[nt], 0, 0, 0);
            }
            #pragma unroll
            for (int r = 0; r < 4; r++) {
                float bs = basisS[w][s][rt * 16 + q * 4 + r];
                #pragma unroll
                for (int nt = 0; nt < 4; nt++)
                    acc[rt][nt][r] = fmaf(bs, ct[nt][r], acc[rt][nt][r]);
            }
        }
    }

    // Epilogue: row-coalesced atomicAdd from C layout (row = q*4+r).
    #pragma unroll
    for (int rt = 0; rt < 4; rt++) {
        #pragma unroll
        for (int r = 0; r < 4; r++) {
            int d = dstS[w][rt * 16 + q * 4 + r];
            if (d >= 0) {
                float* ap = agg + (size_t)d * COUT + colOff + mcol;
                #pragma unroll
                for (int nt = 0; nt < 4; nt++)
                    atomicAdd(ap + nt * 16, acc[rt][nt][r]);
            }
        }
    }
}

// node update (mean + root matmul + bias + elu) + pool scatter, COUT=64.
__global__ __launch_bounds__(256) void node_update64(
    const float* __restrict__ agg, const int* __restrict__ deg,
    const float* __restrict__ xm, const float* __restrict__ root,
    const float* __restrict__ bias, const int* __restrict__ cl,
    unsigned* __restrict__ xmOut, int nNodes) {
    __shared__ float xsh[4][64];
    int w = threadIdx.x >> 6, lane = threadIdx.x & 63;
    int v = blockIdx.x * 4 + w;
    if (v >= nNodes) return;
    xsh[w][lane] = xm[((size_t)v << 6) + lane];
    float a = agg[((size_t)v << 6) + lane] / fmaxf((float)deg[v], 1.0f);
    float r = 0.0f;
    #pragma unroll 8
    for (int i = 0; i < 64; i++)
        r = fmaf(xsh[w][i], root[(i << 6) + lane], r);
    float val = eluf(a + r + bias[lane]);
    atomicMax(&xmOut[((size_t)cl[v] << 6) + lane], f2sort(val));
}

// node update + pool scatter, COUT=128 (2 channels/lane).
__global__ __launch_bounds__(256) void node_update128(
    const float* __restrict__ agg, const int* __restrict__ deg,
    const float* __restrict__ xm, const float* __restrict__ root,
    const float* __restrict__ bias, const int* __restrict__ cl,
    unsigned* __restrict__ xmOut, int nNodes) {
    __shared__ float xsh[4][64];
    int w = threadIdx.x >> 6, lane = threadIdx.x & 63;
    int v = blockIdx.x * 4 + w;
    if (v >= nNodes) return;
    xsh[w][lane] = xm[((size_t)v << 6) + lane];
    float dinv = 1.0f / fmaxf((float)deg[v], 1.0f);
    float a0 = agg[((size_t)v << 7) + lane] * dinv;
    float a1 = agg[((size_t)v << 7) + 64 + lane] * dinv;
    float r0 = 0.0f, r1 = 0.0f;
    #pragma unroll 8
    for (int i = 0; i < 64; i++) {
        float xi = xsh[w][i];
        r0 = fmaf(xi, root[(i << 7) + lane], r0);
        r1 = fmaf(xi, root[(i << 7) + 64 + lane], r1);
    }
    unsigned* orow = xmOut + ((size_t)cl[v] << 7);
    atomicMax(&orow[lane], f2sort(eluf(a0 + r0 + bias[lane])));
    atomicMax(&orow[64 + lane], f2sort(eluf(a1 + r1 + bias[lane + 64])));
}

// fc1 k-split: grid (64 rows, 8 k-slices). Partial dot over 128 inputs,
// atomicAdd into h (zero-initialized).
__global__ __launch_bounds__(256) void fc1_split(
    const float* __restrict__ xin, const float* __restrict__ w1,
    float* __restrict__ h) {
    __shared__ float xsh[128];
    int row = blockIdx.x, ks = blockIdx.y;
    int o = threadIdx.x;
    if (o < 128) xsh[o] = xin[row * 1024 + ks * 128 + o];
    __syncthreads();
    float acc = 0.0f;
    const float* wp = w1 + (size_t)ks * 128 * 256 + o;
    #pragma unroll 8
    for (int i = 0; i < 128; i++)
        acc = fmaf(xsh[i], wp[i * 256], acc);
    atomicAdd(&h[row * 256 + o], acc);
}

// fc2 + log_softmax: elu(h+b1) @ w2 + b2. One block (64 thr) per row.
__global__ __launch_bounds__(64) void fc2_k(
    const float* __restrict__ h, const float* __restrict__ b1,
    const float* __restrict__ w2, const float* __restrict__ b2,
    float* __restrict__ out) {
    __shared__ float hs[256];
    __shared__ float lg[10];
    int row = blockIdx.x;
    int t = threadIdx.x;
    for (int i = t; i < 256; i += 64) hs[i] = eluf(h[row * 256 + i] + b1[i]);
    __syncthreads();
    if (t < 10) {
        float a = b2[t];
        for (int i = 0; i < 256; i++) a = fmaf(hs[i], w2[i * 10 + t], a);
        lg[t] = a;
    }
    __syncthreads();
    if (t < 10) {
        float m = -1e30f;
        #pragma unroll
        for (int j = 0; j < 10; j++) m = fmaxf(m, lg[j]);
        float sum = 0.0f;
        #pragma unroll
        for (int j = 0; j < 10; j++) sum += expf(lg[j] - m);
        out[row * 10 + t] = lg[t] - m - logf(sum);
    }
}

extern "C" void kernel_launch(void* const* d_in, const int* in_sizes, int n_in,
                              void* d_out, int out_size, void* d_ws, size_t ws_size,
                              hipStream_t stream) {
    const float* x0      = (const float*)d_in[0];
    const int*   cluster0= (const int*)d_in[1];
    const int*   edge1   = (const int*)d_in[2];
    const float* pseudo1 = (const float*)d_in[3];
    const float* W1      = (const float*)d_in[4];
    const float* root1   = (const float*)d_in[5];
    const float* b1      = (const float*)d_in[6];
    const int*   cluster1= (const int*)d_in[7];
    const int*   edge2   = (const int*)d_in[8];
    const float* pseudo2 = (const float*)d_in[9];
    const float* W2      = (const float*)d_in[10];
    const float* root2   = (const float*)d_in[11];
    const float* b2      = (const float*)d_in[12];
    const int*   cluster2= (const int*)d_in[13];
    const int*   edge3   = (const int*)d_in[14];
    const float* pseudo3 = (const float*)d_in[15];
    const float* W3      = (const float*)d_in[16];
    const float* root3   = (const float*)d_in[17];
    const float* b3      = (const float*)d_in[18];
    const int*   cluster3= (const int*)d_in[19];
    const float* fc1_w   = (const float*)d_in[20];
    const float* fc1_b   = (const float*)d_in[21];
    const float* fc2_w   = (const float*)d_in[22];
    const float* fc2_b   = (const float*)d_in[23];
    float* out = (float*)d_out;

    float* ws = (float*)d_ws;
    size_t off = 0;
    // ---- zeroed region ----
    float* xm1  = ws + off; off += 20480;
    float* xm2  = ws + off; off += (size_t)N2c * 64;
    float* xm3  = ws + off; off += (size_t)N3c * 64;
    float* xm4  = ws + off; off += 512 * 128;
    float* agg2 = ws + off; off += (size_t)N2c * 64;
    float* agg3 = ws + off; off += (size_t)N3c * 128;
    float* h1   = ws + off; off += 64 * 256;
    int* cntD2   = (int*)(ws + off); off += 6016;
    int* cntD3   = (int*)(ws + off); off += 1664;
    size_t zeroFloats = off;
    // ---- non-zeroed region (fully written before read every launch) ----
    int4* rec1 = (int4*)(ws + off); off += (size_t)E1c * 4;
    int4* rec2 = (int4*)(ws + off); off += (size_t)E2c * 4;
    int4* rec3 = (int4*)(ws + off); off += (size_t)E3c * 4;
    unsigned short* W2t = (unsigned short*)(ws + off); off += 256000;
    unsigned short* W3t = (unsigned short*)(ws + off); off += 512000;
    unsigned short* xb2 = (unsigned short*)(ws + off); off += 192000;
    unsigned short* xb3 = (unsigned short*)(ws + off); off += 51200;
    int* start1    = (int*)(ws + off); off += 1280;
    int* blockCnt1 = (int*)(ws + off); off += HB1 * 1250;
    int* blockOff1 = (int*)(ws + off); off += HB1 * 1250;
    int* blockCnt2 = (int*)(ws + off); off += HB2 * 64;
    int* blockOff2 = (int*)(ws + off); off += HB2 * 64;
    int* blockCnt3 = (int*)(ws + off); off += HB3 * 64;
    int* blockOff3 = (int*)(ws + off); off += HB3 * 64;
    int* binCnt2   = (int*)(ws + off); off += 64;
    int* binStart2 = (int*)(ws + off); off += 80;
    int* blkPrefix2= (int*)(ws + off); off += 80;
    int* chunkBin2 = (int*)(ws + off); off += 2560;
    int* chunkOff2 = (int*)(ws + off); off += 2560;
    int* binCnt3   = (int*)(ws + off); off += 64;
    int* binStart3 = (int*)(ws + off); off += 80;
    int* blkPrefix3= (int*)(ws + off); off += 80;
    int* chunkBin3 = (int*)(ws + off); off += 768;
    int* chunkOff3 = (int*)(ws + off); off += 768;

    hipMemsetAsync(d_ws, 0, zeroFloats * sizeof(float), stream);

    // A: hists + dst-degrees + weight conversion + pool0 scatter
    hist_all<<<HB1 + HB2 + HB3 + CVT2B + CVT3B + SS0B, 256, 0, stream>>>(
        edge1, edge2, edge3, pseudo2, pseudo3, W2, W3, x0, cluster0,
        blockCnt1, blockCnt2, cntD2, blockCnt3, cntD3,
        W2t, W3t, (unsigned*)xm1);

    // B1: per-bin totals + scans + chunk maps
    plan_tot<<<1, 256, 0, stream>>>(
        blockCnt1, start1,
        blockCnt2, binCnt2, binStart2, blkPrefix2, chunkBin2, chunkOff2,
        blockCnt3, binCnt3, binStart3, blkPrefix3, chunkBin3, chunkOff3);

    // B2: per-(bin,block) offsets, one thread per bin-row
    off_all<<<6, 256, 0, stream>>>(
        blockCnt1, start1, blockOff1,
        blockCnt2, binStart2, blockOff2,
        blockCnt3, binStart3, blockOff3);

    // C: scatter edge records + pool0 decode
    scatter_all<<<HB1 + HB2 + HB3 + (N1c + 255) / 256, 256, 0, stream>>>(
        edge1, pseudo1, edge2, pseudo2, edge3, pseudo3,
        blockOff1, blockOff2, blockOff3, rec1, rec2, rec3, (unsigned*)xm1);

    // conv1 (1->64) + pool into xm2
    conv1_block<<<1250, 256, 0, stream>>>(rec1, xm1, start1, W1, root1, b1,
                                          cluster1, (unsigned*)xm2);
    decode_cvt<<<(N2c * 64) / 256, 256, 0, stream>>>((unsigned*)xm2, xb2, N2c * 64);

    // conv2 (64->64): MFMA -> agg2 (atomic), node update + pool into xm3
    spline_mfma<64><<<dim3((E2c / 64 + 64 + 3) / 4, 1), 256, 0, stream>>>(
        rec2, W2t, xb2, binStart2, binCnt2, blkPrefix2, chunkBin2, chunkOff2, agg2);
    node_update64<<<(N2c + 3) / 4, 256, 0, stream>>>(agg2, cntD2, xm2, root2, b2,
                                                     cluster2, (unsigned*)xm3, N2c);
    decode_cvt<<<(N3c * 64) / 256, 256, 0, stream>>>((unsigned*)xm3, xb3, N3c * 64);

    // conv3 (64->128): MFMA -> agg3 (atomic), node update + pool into xm4
    spline_mfma<128><<<dim3((E3c / 64 + 64 + 3) / 4, 2), 256, 0, stream>>>(
        rec3, W3t, xb3, binStart3, binCnt3, blkPrefix3, chunkBin3, chunkOff3, agg3);
    node_update128<<<(N3c + 3) / 4, 256, 0, stream>>>(agg3, cntD3, xm3, root3, b3,
                                                      cluster3, (unsigned*)xm4, N3c);
    segmax_decode<<<(512 * 128) / 256, 256, 0, stream>>>((unsigned*)xm4, 512 * 128);

    // FC head: k-split fc1 + fused fc2/log_softmax
    fc1_split<<<dim3(64, 8), 256, 0, stream>>>(xm4, fc1_w, h1);
    fc2_k<<<64, 64, 0, stream>>>(h1, fc1_b, fc2_w, fc2_b, out);
}